// Round 1
// baseline (378.384 us; speedup 1.0000x reference)
//
#include <hip/hip_runtime.h>
#include <stdint.h>

typedef float f32x4 __attribute__((ext_vector_type(4)));
typedef short bf16x8 __attribute__((ext_vector_type(8)));

#define LD 68        // LDS row stride in floats (16B-aligned rows, de-conflicted)
#define NPTS 32      // points per wave; state rows = 3*NPTS = 96

// pack {odd[31:16] : even[31:16]} -> one u32 holding two bf16 (even in low half)
__device__ __forceinline__ uint32_t prm_hi(uint32_t odd, uint32_t even) {
  return __builtin_amdgcn_perm(odd, even, 0x07060302u);
}

__device__ __forceinline__ float fast_tanh(float z) {
  float e = __expf(2.f * z);          // v_exp based fast exp
  float d = e + 1.f;
  float r;
  asm("v_rcp_f32 %0, %1" : "=v"(r) : "v"(d));
  return fmaf(-2.f, r, 1.f);          // 1 - 2/(e^{2z}+1); saturates correctly at +-1
}

__device__ __forceinline__ f32x4 mfma16(bf16x8 a, bf16x8 b, f32x4 c) {
  return __builtin_amdgcn_mfma_f32_16x16x32_bf16(a, b, c, 0, 0, 0);
}

// read 8 consecutive fp32 from LDS, emit hi (truncated bf16) and lo (residual, truncated bf16) frags
__device__ __forceinline__ void split8(const float* src, bf16x8& hi, bf16x8& lo) {
  f32x4 v0 = *(const f32x4*)(src);
  f32x4 v1 = *(const f32x4*)(src + 4);
  float vv[8];
  #pragma unroll
  for (int j = 0; j < 4; ++j) { vv[j] = v0[j]; vv[4 + j] = v1[j]; }
  uint32_t u[8], w[8];
  #pragma unroll
  for (int j = 0; j < 8; ++j) {
    uint32_t uu = __float_as_uint(vv[j]);
    float hf = __uint_as_float(uu & 0xFFFF0000u);
    u[j] = uu;
    w[j] = __float_as_uint(vv[j] - hf);   // exact residual in f32
  }
  uint4 H, L;
  H.x = prm_hi(u[1], u[0]); H.y = prm_hi(u[3], u[2]);
  H.z = prm_hi(u[5], u[4]); H.w = prm_hi(u[7], u[6]);
  L.x = prm_hi(w[1], w[0]); L.y = prm_hi(w[3], w[2]);
  L.z = prm_hi(w[5], w[4]); L.w = prm_hi(w[7], w[6]);
  hi = __builtin_bit_cast(bf16x8, H);
  lo = __builtin_bit_cast(bf16x8, L);
}

// Pre-split Ws (7 x 64 x 64 fp32) into hi/lo bf16 B-fragments, frag-layout-major.
// Frag f = (l*4 + nt)*2 + kk ; lane holds 8 bf16 at line(col)=nt*16+(lane&15),
// k = kk*32 + (lane>>4)*8 + j  (same convention as the A-side build -> permutation cancels)
__global__ void __launch_bounds__(64) prep_kernel(const float* __restrict__ Ws,
                                                  uint4* __restrict__ whi,
                                                  uint4* __restrict__ wlo) {
  int f = blockIdx.x, lane = threadIdx.x;
  int kk = f & 1, nt = (f >> 1) & 3, l = f >> 3;
  int col = nt * 16 + (lane & 15);
  int k0 = kk * 32 + (lane >> 4) * 8;
  uint32_t u[8], w[8];
  #pragma unroll
  for (int j = 0; j < 8; ++j) {
    float v = Ws[l * 4096 + (k0 + j) * 64 + col];
    uint32_t uu = __float_as_uint(v);
    float hf = __uint_as_float(uu & 0xFFFF0000u);
    u[j] = uu;
    w[j] = __float_as_uint(v - hf);
  }
  uint4 H, L;
  H.x = prm_hi(u[1], u[0]); H.y = prm_hi(u[3], u[2]);
  H.z = prm_hi(u[5], u[4]); H.w = prm_hi(u[7], u[6]);
  L.x = prm_hi(w[1], w[0]); L.y = prm_hi(w[3], w[2]);
  L.z = prm_hi(w[5], w[4]); L.w = prm_hi(w[7], w[6]);
  whi[f * 64 + lane] = H;
  wlo[f * 64 + lane] = L;
}

// One wave (64 threads) per block, NPTS=32 points per wave, fully independent.
// State rows: Y = 0..31, T0 = 32..63, T1 = 64..95 (m-tiles 0..5 of 16 rows).
__global__ void __launch_bounds__(64) velprevec_kernel(
    const float* __restrict__ x, const float* __restrict__ Win,
    const float* __restrict__ bin, const float* __restrict__ bs,
    const float* __restrict__ Wout, const uint4* __restrict__ whi,
    const uint4* __restrict__ wlo, float* __restrict__ out) {
  __shared__ float st[96 * LD + 128];
  const int lane = threadIdx.x;
  const int p0 = blockIdx.x * NPTS;
  const int pr = lane & 15, g = lane >> 4;

  // ---- layer 0 (3->64 linear, no activation) + tangent init (rows of W_in) ----
  #pragma unroll
  for (int pp = 0; pp < 2; ++pp) {
    int p = pr + pp * 16;
    const float* xp = &x[(p0 + p) * 3];
    float x0 = xp[0], x1 = xp[1], x2 = xp[2];
    #pragma unroll
    for (int cc = 0; cc < 16; ++cc) {
      int c = g * 16 + cc;
      float w0 = Win[c], w1 = Win[64 + c], w2 = Win[128 + c];
      st[p * LD + c]        = fmaf(x0, w0, fmaf(x1, w1, fmaf(x2, w2, bin[c])));
      st[(32 + p) * LD + c] = w0;   // t0 = d y0 / d x0 = W_in row 0
      st[(64 + p) * LD + c] = w1;   // t1 = d y0 / d x1 = W_in row 1
    }
  }
  st[96 * LD + lane]      = Wout[lane * 2 + 0];
  st[96 * LD + 64 + lane] = Wout[lane * 2 + 1];

  // ---- 7 hidden layers: z=Y@W+b, Y'=tanh(z), T'=(1-Y'^2) o (T@W), split-bf16 3-term MFMA ----
  for (int l = 0; l < 7; ++l) {
    uint4 wh[4][2], wl[4][2];
    #pragma unroll
    for (int nt = 0; nt < 4; ++nt)
      #pragma unroll
      for (int kk = 0; kk < 2; ++kk) {
        int f = (l * 4 + nt) * 2 + kk;
        wh[nt][kk] = whi[f * 64 + lane];
        wl[nt][kk] = wlo[f * 64 + lane];
      }
    float bias[4];
    #pragma unroll
    for (int nt = 0; nt < 4; ++nt) bias[nt] = bs[l * 64 + nt * 16 + pr];

    f32x4 acc[6][4];
    #pragma unroll
    for (int mt = 0; mt < 6; ++mt)
      #pragma unroll
      for (int nt = 0; nt < 4; ++nt) acc[mt][nt] = (f32x4){0.f, 0.f, 0.f, 0.f};

    #pragma unroll
    for (int mt = 0; mt < 6; ++mt) {
      bf16x8 ah[2], al[2];
      #pragma unroll
      for (int kk = 0; kk < 2; ++kk)
        split8(&st[(mt * 16 + pr) * LD + kk * 32 + g * 8], ah[kk], al[kk]);
      #pragma unroll
      for (int nt = 0; nt < 4; ++nt) {
        f32x4 a = acc[mt][nt];
        #pragma unroll
        for (int kk = 0; kk < 2; ++kk) {
          bf16x8 bh = __builtin_bit_cast(bf16x8, wh[nt][kk]);
          bf16x8 bl = __builtin_bit_cast(bf16x8, wl[nt][kk]);
          a = mfma16(ah[kk], bh, a);   // hi*hi
          a = mfma16(ah[kk], bl, a);   // hi*lo
          a = mfma16(al[kk], bh, a);   // lo*hi
        }
        acc[mt][nt] = a;
      }
    }

    // epilogue: C layout col=lane&15, row=(lane>>4)*4+i (HW-verified).
    // Y-tile yt and T-tiles 2+yt / 4+yt hold matching rows in the same lane.
    #pragma unroll
    for (int yt = 0; yt < 2; ++yt)
      #pragma unroll
      for (int nt = 0; nt < 4; ++nt) {
        int col = nt * 16 + pr;
        #pragma unroll
        for (int i = 0; i < 4; ++i) {
          int p = yt * 16 + g * 4 + i;
          float z = acc[yt][nt][i] + bias[nt];
          float t = fast_tanh(z);
          float s = fmaf(-t, t, 1.f);
          st[p * LD + col]        = t;
          st[(32 + p) * LD + col] = s * acc[2 + yt][nt][i];
          st[(64 + p) * LD + col] = s * acc[4 + yt][nt][i];
        }
      }
  }

  // ---- output layer: J[o][j] = t_j @ Wout[:,o];  u = [J01, -J00, J10, J11] ----
  #pragma unroll
  for (int h = 0; h < 2; ++h) {
    int idx = h * 64 + lane;
    int p = idx >> 2, m = idx & 3;
    int j = (m == 0 || m == 3) ? 1 : 0;
    int o = m >> 1;
    float sgn = (m == 1) ? -1.f : 1.f;
    const float* trow = &st[(32 + 32 * j + p) * LD];
    const float* wo   = &st[96 * LD + o * 64];
    float a = 0.f;
    #pragma unroll
    for (int k = 0; k < 64; k += 4) {
      f32x4 tv = *(const f32x4*)(trow + k);
      f32x4 wv = *(const f32x4*)(wo + k);
      a = fmaf(tv[3], wv[3], fmaf(tv[2], wv[2], fmaf(tv[1], wv[1], fmaf(tv[0], wv[0], a))));
    }
    out[(p0 + p) * 4 + m] = sgn * a;
  }
}

extern "C" void kernel_launch(void* const* d_in, const int* in_sizes, int n_in,
                              void* d_out, int out_size, void* d_ws, size_t ws_size,
                              hipStream_t stream) {
  const float* x    = (const float*)d_in[0];
  const float* Win  = (const float*)d_in[1];
  const float* bin  = (const float*)d_in[2];
  const float* Ws   = (const float*)d_in[3];
  const float* bs   = (const float*)d_in[4];
  const float* Wout = (const float*)d_in[5];
  float* out = (float*)d_out;

  uint4* whi = (uint4*)d_ws;
  uint4* wlo = whi + 56 * 64;   // 56 frags * 64 lanes * 16B each for hi and lo

  int N = in_sizes[0] / 3;      // 524288

  prep_kernel<<<56, 64, 0, stream>>>(Ws, whi, wlo);
  velprevec_kernel<<<N / NPTS, 64, 0, stream>>>(x, Win, bin, bs, Wout, whi, wlo, out);
}

// Round 2
// 336.474 us; speedup vs baseline: 1.1246x; 1.1246x over previous
//
#include <hip/hip_runtime.h>
#include <stdint.h>

typedef float f32x4 __attribute__((ext_vector_type(4)));
typedef short bf16x8 __attribute__((ext_vector_type(8)));

#define LD 68        // LDS row stride in floats (16B-aligned rows)
#define NPTS 16      // points per wave; state rows = 3*NPTS = 48
#define TANH_C 2.885390081777927f   // 2*log2(e)

// pack {odd[31:16] : even[31:16]} -> one u32 holding two bf16 (even in low half)
__device__ __forceinline__ uint32_t prm_hi(uint32_t odd, uint32_t even) {
  return __builtin_amdgcn_perm(odd, even, 0x07060302u);
}

__device__ __forceinline__ float rcp_fast(float d) {
  float r;
  asm("v_rcp_f32 %0, %1" : "=v"(r) : "v"(d));
  return r;
}
__device__ __forceinline__ float exp2_fast(float x) {
  float r;
  asm("v_exp_f32 %0, %1" : "=v"(r) : "v"(x));
  return r;
}

__device__ __forceinline__ f32x4 mfma16(bf16x8 a, bf16x8 b, f32x4 c) {
  return __builtin_amdgcn_mfma_f32_16x16x32_bf16(a, b, c, 0, 0, 0);
}

// read 8 consecutive fp32 from LDS, emit hi (truncated bf16) and lo (residual) frags
__device__ __forceinline__ void split8(const float* src, bf16x8& hi, bf16x8& lo) {
  f32x4 v0 = *(const f32x4*)(src);
  f32x4 v1 = *(const f32x4*)(src + 4);
  float vv[8];
  #pragma unroll
  for (int j = 0; j < 4; ++j) { vv[j] = v0[j]; vv[4 + j] = v1[j]; }
  uint32_t u[8], w[8];
  #pragma unroll
  for (int j = 0; j < 8; ++j) {
    uint32_t uu = __float_as_uint(vv[j]);
    float hf = __uint_as_float(uu & 0xFFFF0000u);
    u[j] = uu;
    w[j] = __float_as_uint(vv[j] - hf);   // exact residual in f32
  }
  uint4 H, L;
  H.x = prm_hi(u[1], u[0]); H.y = prm_hi(u[3], u[2]);
  H.z = prm_hi(u[5], u[4]); H.w = prm_hi(u[7], u[6]);
  L.x = prm_hi(w[1], w[0]); L.y = prm_hi(w[3], w[2]);
  L.z = prm_hi(w[5], w[4]); L.w = prm_hi(w[7], w[6]);
  hi = __builtin_bit_cast(bf16x8, H);
  lo = __builtin_bit_cast(bf16x8, L);
}

// Pre-split Ws (7 x 64 x 64 fp32) into hi/lo bf16 B-fragments, frag-layout-major.
// Frag f = (l*4 + nt)*2 + kk ; lane holds 8 bf16 at col=nt*16+(lane&15),
// k = kk*32 + (lane>>4)*8 + j  (same convention as the A-side build)
__global__ void __launch_bounds__(64) prep_kernel(const float* __restrict__ Ws,
                                                  uint4* __restrict__ whi,
                                                  uint4* __restrict__ wlo) {
  int f = blockIdx.x, lane = threadIdx.x;
  int kk = f & 1, nt = (f >> 1) & 3, l = f >> 3;
  int col = nt * 16 + (lane & 15);
  int k0 = kk * 32 + (lane >> 4) * 8;
  uint32_t u[8], w[8];
  #pragma unroll
  for (int j = 0; j < 8; ++j) {
    float v = Ws[l * 4096 + (k0 + j) * 64 + col];
    uint32_t uu = __float_as_uint(v);
    float hf = __uint_as_float(uu & 0xFFFF0000u);
    u[j] = uu;
    w[j] = __float_as_uint(v - hf);
  }
  uint4 H, L;
  H.x = prm_hi(u[1], u[0]); H.y = prm_hi(u[3], u[2]);
  H.z = prm_hi(u[5], u[4]); H.w = prm_hi(u[7], u[6]);
  L.x = prm_hi(w[1], w[0]); L.y = prm_hi(w[3], w[2]);
  L.z = prm_hi(w[5], w[4]); L.w = prm_hi(w[7], w[6]);
  whi[f * 64 + lane] = H;
  wlo[f * 64 + lane] = L;
}

// One wave per block, NPTS=16 points. State rows: Y=0..15, T0=16..31, T1=32..47.
__global__ void __launch_bounds__(64, 3) velprevec_kernel(
    const float* __restrict__ x, const float* __restrict__ Win,
    const float* __restrict__ bin, const float* __restrict__ bs,
    const float* __restrict__ Wout, const uint4* __restrict__ whi,
    const uint4* __restrict__ wlo, float* __restrict__ out) {
  __shared__ float st[48 * LD + 128];
  const int lane = threadIdx.x;
  const int p0 = blockIdx.x * NPTS;
  const int pr = lane & 15, g = lane >> 4;

  // ---- layer 0 (3->64 linear, no activation) + tangent init (rows of W_in) ----
  {
    const float* xp = &x[(p0 + pr) * 3];
    float x0 = xp[0], x1 = xp[1], x2 = xp[2];
    #pragma unroll
    for (int cc = 0; cc < 16; ++cc) {
      int c = g * 16 + cc;
      float w0 = Win[c], w1 = Win[64 + c], w2 = Win[128 + c];
      st[pr * LD + c]        = fmaf(x0, w0, fmaf(x1, w1, fmaf(x2, w2, bin[c])));
      st[(16 + pr) * LD + c] = w0;   // t0 = d y0/d x0
      st[(32 + pr) * LD + c] = w1;   // t1 = d y0/d x1
    }
  }
  st[48 * LD + lane]      = Wout[lane * 2 + 0];
  st[48 * LD + 64 + lane] = Wout[lane * 2 + 1];

  // ---- 7 hidden layers: z=Y@W+b, Y'=tanh(z), T'=(1-Y'^2) o (T@W) ----
  for (int l = 0; l < 7; ++l) {
    uint4 wh[4][2], wl[4][2];
    #pragma unroll
    for (int nt = 0; nt < 4; ++nt)
      #pragma unroll
      for (int kk = 0; kk < 2; ++kk) {
        int f = (l * 4 + nt) * 2 + kk;
        wh[nt][kk] = whi[f * 64 + lane];
        wl[nt][kk] = wlo[f * 64 + lane];
      }
    float bias2[4];
    #pragma unroll
    for (int nt = 0; nt < 4; ++nt) bias2[nt] = bs[l * 64 + nt * 16 + pr] * TANH_C;

    f32x4 acc[3][4];
    #pragma unroll
    for (int mt = 0; mt < 3; ++mt)
      #pragma unroll
      for (int nt = 0; nt < 4; ++nt) acc[mt][nt] = (f32x4){0.f, 0.f, 0.f, 0.f};

    #pragma unroll
    for (int mt = 0; mt < 3; ++mt) {
      bf16x8 ah[2], al[2];
      #pragma unroll
      for (int kk = 0; kk < 2; ++kk)
        split8(&st[(mt * 16 + pr) * LD + kk * 32 + g * 8], ah[kk], al[kk]);
      // nt innermost: 4 independent accumulator chains between dependent MFMAs
      #pragma unroll
      for (int kk = 0; kk < 2; ++kk) {
        #pragma unroll
        for (int nt = 0; nt < 4; ++nt)
          acc[mt][nt] = mfma16(ah[kk], __builtin_bit_cast(bf16x8, wh[nt][kk]), acc[mt][nt]);
        #pragma unroll
        for (int nt = 0; nt < 4; ++nt)
          acc[mt][nt] = mfma16(ah[kk], __builtin_bit_cast(bf16x8, wl[nt][kk]), acc[mt][nt]);
        #pragma unroll
        for (int nt = 0; nt < 4; ++nt)
          acc[mt][nt] = mfma16(al[kk], __builtin_bit_cast(bf16x8, wh[nt][kk]), acc[mt][nt]);
      }
    }

    // epilogue: C layout col=lane&15, row=(lane>>4)*4+i
    #pragma unroll
    for (int nt = 0; nt < 4; ++nt) {
      int col = nt * 16 + pr;
      #pragma unroll
      for (int i = 0; i < 4; ++i) {
        int p = g * 4 + i;
        float e = exp2_fast(fmaf(acc[0][nt][i], TANH_C, bias2[nt]));
        float r = rcp_fast(e + 1.f);
        float t = fmaf(-2.f, r, 1.f);         // tanh(z)
        float s = fmaf(-t, t, 1.f);           // sech^2(z)
        st[p * LD + col]        = t;
        st[(16 + p) * LD + col] = s * acc[1][nt][i];
        st[(32 + p) * LD + col] = s * acc[2][nt][i];
      }
    }
  }

  // ---- output layer: J[o][j] = t_j @ Wout[:,o];  u = [J01, -J00, J10, J11] ----
  {
    int p = lane >> 2, m = lane & 3;
    int j = (m == 0 || m == 3) ? 1 : 0;
    int o = m >> 1;
    float sgn = (m == 1) ? -1.f : 1.f;
    const float* trow = &st[(16 + 16 * j + p) * LD];
    const float* wo   = &st[48 * LD + o * 64];
    float a = 0.f;
    #pragma unroll
    for (int k = 0; k < 64; k += 4) {
      f32x4 tv = *(const f32x4*)(trow + k);
      f32x4 wv = *(const f32x4*)(wo + k);
      a = fmaf(tv[3], wv[3], fmaf(tv[2], wv[2], fmaf(tv[1], wv[1], fmaf(tv[0], wv[0], a))));
    }
    out[(p0 + p) * 4 + m] = sgn * a;
  }
}

extern "C" void kernel_launch(void* const* d_in, const int* in_sizes, int n_in,
                              void* d_out, int out_size, void* d_ws, size_t ws_size,
                              hipStream_t stream) {
  const float* x    = (const float*)d_in[0];
  const float* Win  = (const float*)d_in[1];
  const float* bin  = (const float*)d_in[2];
  const float* Ws   = (const float*)d_in[3];
  const float* bs   = (const float*)d_in[4];
  const float* Wout = (const float*)d_in[5];
  float* out = (float*)d_out;

  uint4* whi = (uint4*)d_ws;
  uint4* wlo = whi + 56 * 64;   // 56 frags * 64 lanes * 16B each for hi and lo

  int N = in_sizes[0] / 3;      // 524288

  prep_kernel<<<56, 64, 0, stream>>>(Ws, whi, wlo);
  velprevec_kernel<<<N / NPTS, 64, 0, stream>>>(x, Win, bin, bs, Wout, whi, wlo, out);
}

// Round 3
// 312.727 us; speedup vs baseline: 1.2099x; 1.0759x over previous
//
#include <hip/hip_runtime.h>
#include <stdint.h>

typedef float f32x4 __attribute__((ext_vector_type(4)));
typedef short bf16x8 __attribute__((ext_vector_type(8)));

#define TANH_C 2.885390081777927f   // 2*log2(e)

// pack {odd[31:16] : even[31:16]} -> one u32 of two bf16 (even in low half)
__device__ __forceinline__ uint32_t prm_hi(uint32_t odd, uint32_t even) {
  return __builtin_amdgcn_perm(odd, even, 0x07060302u);
}
__device__ __forceinline__ float rcp_fast(float d) {
  float r; asm("v_rcp_f32 %0, %1" : "=v"(r) : "v"(d)); return r;
}
__device__ __forceinline__ float exp2_fast(float x) {
  float r; asm("v_exp_f32 %0, %1" : "=v"(r) : "v"(x)); return r;
}
__device__ __forceinline__ f32x4 mfma16(bf16x8 a, bf16x8 b, f32x4 c) {
  return __builtin_amdgcn_mfma_f32_16x16x32_bf16(a, b, c, 0, 0, 0);
}
__device__ __forceinline__ bf16x8 bc(uint4 v) { return __builtin_bit_cast(bf16x8, v); }

// Pack 16 f32 (C-layout accs v[mt][i] = X^T[16mt+4g+i][p]) into hi/lo B-frags.
// Slot convention: frag kk, word w, half h  <->  logical k = 16*(2kk+(w>>1)) + 4g + 2*(w&1) + h
// (A-side in prep_kernel uses the same convention, so the permutation cancels.)
__device__ __forceinline__ void pack16(const float v[4][4], uint4 H[2], uint4 L[2]) {
  uint32_t hw[8], lw[8];
  #pragma unroll
  for (int kk = 0; kk < 2; ++kk)
    #pragma unroll
    for (int w = 0; w < 4; ++w) {
      int mt = 2 * kk + (w >> 1), ie = 2 * (w & 1);
      float ve = v[mt][ie], vo = v[mt][ie + 1];
      uint32_t ue = __float_as_uint(ve), uo = __float_as_uint(vo);
      float he = __uint_as_float(ue & 0xFFFF0000u);
      float ho = __uint_as_float(uo & 0xFFFF0000u);
      hw[kk * 4 + w] = prm_hi(uo, ue);
      lw[kk * 4 + w] = prm_hi(__float_as_uint(vo - ho), __float_as_uint(ve - he));
    }
  H[0] = (uint4){hw[0], hw[1], hw[2], hw[3]};
  H[1] = (uint4){hw[4], hw[5], hw[6], hw[7]};
  L[0] = (uint4){lw[0], lw[1], lw[2], lw[3]};
  L[1] = (uint4){lw[4], lw[5], lw[6], lw[7]};
}

// butterfly reduce across the four 16-lane groups (xor16 via ds_swizzle, xor32 via permlane32_swap)
__device__ __forceinline__ float xreduce(float v) {
  int t = __builtin_amdgcn_ds_swizzle(__float_as_int(v), 0x401F); // lane ^= 16 (within 32)
  v += __int_as_float(t);
  float a = v, b = v;
  asm volatile("v_permlane32_swap_b32 %0, %1" : "+v"(a), "+v"(b));
  return a + b;   // lane i: v[i] + v[i^32]
}

// Pre-split A = W^T into hi/lo bf16 A-frags. Frag f = (l*4+mt)*2+kk.
// Lane (r=lane&15, g=lane>>4): row_out = 16mt+r; slot (w,h) holds
// W^T[row_out][k] = Ws[l][k][row_out] with k = 16*(2kk+(w>>1)) + 4g + 2*(w&1) + h.
__global__ void __launch_bounds__(64) prep_kernel(const float* __restrict__ Ws,
                                                  uint4* __restrict__ whi,
                                                  uint4* __restrict__ wlo) {
  int f = blockIdx.x, lane = threadIdx.x;
  int kk = f & 1, mt = (f >> 1) & 3, l = f >> 3;
  int r = lane & 15, g = lane >> 4;
  uint32_t hw[4], lw[4];
  #pragma unroll
  for (int w = 0; w < 4; ++w) {
    uint32_t uu[2], res[2];
    #pragma unroll
    for (int h = 0; h < 2; ++h) {
      int k = 16 * (2 * kk + (w >> 1)) + 4 * g + 2 * (w & 1) + h;
      float v = Ws[l * 4096 + k * 64 + 16 * mt + r];
      uu[h] = __float_as_uint(v);
      res[h] = __float_as_uint(v - __uint_as_float(uu[h] & 0xFFFF0000u));
    }
    hw[w] = prm_hi(uu[1], uu[0]);
    lw[w] = prm_hi(res[1], res[0]);
  }
  whi[f * 64 + lane] = (uint4){hw[0], hw[1], hw[2], hw[3]};
  wlo[f * 64 + lane] = (uint4){lw[0], lw[1], lw[2], lw[3]};
}

// Fully register-resident: one wave per block, 16 points (p = lane&15).
// State held transposed (X^T), distributed as MFMA C-layout; repack to B-frags is in-lane.
__global__ void __launch_bounds__(64, 3) velprevec_kernel(
    const float* __restrict__ x, const float* __restrict__ Win,
    const float* __restrict__ bin, const float* __restrict__ bs,
    const float* __restrict__ Wout, const uint4* __restrict__ whi,
    const uint4* __restrict__ wlo, float* __restrict__ out) {
  const int lane = threadIdx.x;
  const int p0 = blockIdx.x * 16;
  const int p = lane & 15, g = lane >> 4;
  const int fb = 4 * g;

  // ---- layer 0: Y = x@Win + bin (no activation); T0 = Win row0, T1 = Win row1 ----
  const float* xp = &x[(p0 + p) * 3];
  float x0 = xp[0], x1 = xp[1], x2 = xp[2];

  uint4 BYh[2], BYl[2], B0h[2], B0l[2], B1h[2], B1l[2];
  {
    float Yv[4][4], T0v[4][4], T1v[4][4];
    #pragma unroll
    for (int mt = 0; mt < 4; ++mt) {
      f32x4 w0 = *(const f32x4*)&Win[      16 * mt + fb];
      f32x4 w1 = *(const f32x4*)&Win[ 64 + 16 * mt + fb];
      f32x4 w2 = *(const f32x4*)&Win[128 + 16 * mt + fb];
      f32x4 bb = *(const f32x4*)&bin[      16 * mt + fb];
      #pragma unroll
      for (int i = 0; i < 4; ++i) {
        Yv[mt][i]  = fmaf(x0, w0[i], fmaf(x1, w1[i], fmaf(x2, w2[i], bb[i])));
        T0v[mt][i] = w0[i];
        T1v[mt][i] = w1[i];
      }
    }
    pack16(Yv, BYh, BYl);
    pack16(T0v, B0h, B0l);
    pack16(T1v, B1h, B1l);
  }

  float T0n[4][4], T1n[4][4];

  // ---- 7 hidden layers, zero LDS ----
  #pragma unroll 1
  for (int l = 0; l < 7; ++l) {
    const uint4* ph  = whi + l * 8 * 64 + lane;
    const uint4* pl_ = wlo + l * 8 * 64 + lane;
    f32x4 aY[4], a0[4], a1[4];
    #pragma unroll
    for (int mt = 0; mt < 4; ++mt) {
      aY[mt] = (f32x4){0.f, 0.f, 0.f, 0.f};
      a0[mt] = (f32x4){0.f, 0.f, 0.f, 0.f};
      a1[mt] = (f32x4){0.f, 0.f, 0.f, 0.f};
    }
    #pragma unroll
    for (int kk = 0; kk < 2; ++kk) {
      uint4 Ah[4], Al[4];
      #pragma unroll
      for (int mt = 0; mt < 4; ++mt) {
        Ah[mt] = ph[(mt * 2 + kk) * 64];
        Al[mt] = pl_[(mt * 2 + kk) * 64];
      }
      bf16x8 bYh = bc(BYh[kk]), bYl = bc(BYl[kk]);
      bf16x8 b0h = bc(B0h[kk]), b0l = bc(B0l[kk]);
      bf16x8 b1h = bc(B1h[kk]), b1l = bc(B1l[kk]);
      #pragma unroll
      for (int mt = 0; mt < 4; ++mt) aY[mt] = mfma16(bc(Ah[mt]), bYh, aY[mt]);
      #pragma unroll
      for (int mt = 0; mt < 4; ++mt) a0[mt] = mfma16(bc(Ah[mt]), b0h, a0[mt]);
      #pragma unroll
      for (int mt = 0; mt < 4; ++mt) a1[mt] = mfma16(bc(Ah[mt]), b1h, a1[mt]);
      #pragma unroll
      for (int mt = 0; mt < 4; ++mt) aY[mt] = mfma16(bc(Ah[mt]), bYl, aY[mt]);
      #pragma unroll
      for (int mt = 0; mt < 4; ++mt) a0[mt] = mfma16(bc(Ah[mt]), b0l, a0[mt]);
      #pragma unroll
      for (int mt = 0; mt < 4; ++mt) a1[mt] = mfma16(bc(Ah[mt]), b1l, a1[mt]);
      #pragma unroll
      for (int mt = 0; mt < 4; ++mt) aY[mt] = mfma16(bc(Al[mt]), bYh, aY[mt]);
      #pragma unroll
      for (int mt = 0; mt < 4; ++mt) a0[mt] = mfma16(bc(Al[mt]), b0h, a0[mt]);
      #pragma unroll
      for (int mt = 0; mt < 4; ++mt) a1[mt] = mfma16(bc(Al[mt]), b1h, a1[mt]);
    }
    // epilogue: tanh + tangent scale, all in-register
    float Yn[4][4];
    #pragma unroll
    for (int mt = 0; mt < 4; ++mt) {
      f32x4 bb = *(const f32x4*)&bs[l * 64 + 16 * mt + fb];
      #pragma unroll
      for (int i = 0; i < 4; ++i) {
        float e = exp2_fast((aY[mt][i] + bb[i]) * TANH_C);
        float r = rcp_fast(e + 1.f);
        float t = fmaf(-2.f, r, 1.f);     // tanh(z)
        float s = fmaf(-t, t, 1.f);       // sech^2(z)
        Yn[mt][i]  = t;
        T0n[mt][i] = s * a0[mt][i];
        T1n[mt][i] = s * a1[mt][i];
      }
    }
    if (l < 6) {
      pack16(Yn, BYh, BYl);
      pack16(T0n, B0h, B0l);
      pack16(T1n, B1h, B1l);
    }
  }

  // ---- output: J_{jo} = T_j . Wout[:,o];  u = [J10, -J00, J01, J11] ----
  float J00 = 0.f, J01 = 0.f, J10 = 0.f, J11 = 0.f;
  #pragma unroll
  for (int mt = 0; mt < 4; ++mt) {
    f32x4 wa = *(const f32x4*)&Wout[(16 * mt + fb) * 2];      // feats f0,f1: (W0,W1,W0,W1)
    f32x4 wb = *(const f32x4*)&Wout[(16 * mt + fb) * 2 + 4];  // feats f2,f3
    J00 = fmaf(T0n[mt][0], wa[0], fmaf(T0n[mt][1], wa[2], fmaf(T0n[mt][2], wb[0], fmaf(T0n[mt][3], wb[2], J00))));
    J01 = fmaf(T0n[mt][0], wa[1], fmaf(T0n[mt][1], wa[3], fmaf(T0n[mt][2], wb[1], fmaf(T0n[mt][3], wb[3], J01))));
    J10 = fmaf(T1n[mt][0], wa[0], fmaf(T1n[mt][1], wa[2], fmaf(T1n[mt][2], wb[0], fmaf(T1n[mt][3], wb[2], J10))));
    J11 = fmaf(T1n[mt][0], wa[1], fmaf(T1n[mt][1], wa[3], fmaf(T1n[mt][2], wb[1], fmaf(T1n[mt][3], wb[3], J11))));
  }
  J00 = xreduce(J00); J01 = xreduce(J01); J10 = xreduce(J10); J11 = xreduce(J11);
  float val = (g == 0) ? J10 : (g == 1) ? -J00 : (g == 2) ? J01 : J11;
  out[(p0 + p) * 4 + g] = val;
}

extern "C" void kernel_launch(void* const* d_in, const int* in_sizes, int n_in,
                              void* d_out, int out_size, void* d_ws, size_t ws_size,
                              hipStream_t stream) {
  const float* x    = (const float*)d_in[0];
  const float* Win  = (const float*)d_in[1];
  const float* bin  = (const float*)d_in[2];
  const float* Ws   = (const float*)d_in[3];
  const float* bs   = (const float*)d_in[4];
  const float* Wout = (const float*)d_in[5];
  float* out = (float*)d_out;

  uint4* whi = (uint4*)d_ws;
  uint4* wlo = whi + 56 * 64;

  int N = in_sizes[0] / 3;      // 524288

  prep_kernel<<<56, 64, 0, stream>>>(Ws, whi, wlo);
  velprevec_kernel<<<N / 16, 64, 0, stream>>>(x, Win, bin, bs, Wout, whi, wlo, out);
}

// Round 4
// 265.990 us; speedup vs baseline: 1.4225x; 1.1757x over previous
//
#include <hip/hip_runtime.h>
#include <stdint.h>

typedef float f32x4 __attribute__((ext_vector_type(4)));
typedef short bf16x8 __attribute__((ext_vector_type(8)));

#define TANH_C 2.885390081777927f   // 2*log2(e)

// pack {odd[31:16] : even[31:16]} -> one u32 of two bf16 (even in low half)
__device__ __forceinline__ uint32_t prm_hi(uint32_t odd, uint32_t even) {
  return __builtin_amdgcn_perm(odd, even, 0x07060302u);
}
__device__ __forceinline__ float rcp_fast(float d) {
  float r; asm("v_rcp_f32 %0, %1" : "=v"(r) : "v"(d)); return r;
}
__device__ __forceinline__ float exp2_fast(float x) {
  float r; asm("v_exp_f32 %0, %1" : "=v"(r) : "v"(x)); return r;
}
__device__ __forceinline__ f32x4 mfma16(bf16x8 a, bf16x8 b, f32x4 c) {
  return __builtin_amdgcn_mfma_f32_16x16x32_bf16(a, b, c, 0, 0, 0);
}
__device__ __forceinline__ bf16x8 bc(uint4 v) { return __builtin_bit_cast(bf16x8, v); }

// ---- hi/lo split pack (Y state): trunc hi + residual lo ----
// Slot convention: frag kk, word w, half h <-> k = 16*(2kk+(w>>1)) + 4g + 2*(w&1) + h
__device__ __forceinline__ void pack16(const float v[4][4], uint4 H[2], uint4 L[2]) {
  uint32_t hw[8], lw[8];
  #pragma unroll
  for (int kk = 0; kk < 2; ++kk)
    #pragma unroll
    for (int w = 0; w < 4; ++w) {
      int mt = 2 * kk + (w >> 1), ie = 2 * (w & 1);
      float ve = v[mt][ie], vo = v[mt][ie + 1];
      uint32_t ue = __float_as_uint(ve), uo = __float_as_uint(vo);
      float he = __uint_as_float(ue & 0xFFFF0000u);
      float ho = __uint_as_float(uo & 0xFFFF0000u);
      hw[kk * 4 + w] = prm_hi(uo, ue);
      lw[kk * 4 + w] = prm_hi(__float_as_uint(vo - ho), __float_as_uint(ve - he));
    }
  H[0] = (uint4){hw[0], hw[1], hw[2], hw[3]};
  H[1] = (uint4){hw[4], hw[5], hw[6], hw[7]};
  L[0] = (uint4){lw[0], lw[1], lw[2], lw[3]};
  L[1] = (uint4){lw[4], lw[5], lw[6], lw[7]};
}

// ---- single-bf16 RNE pack (T states): v_cvt_pk_bf16_f32, even elem in low half ----
__device__ __forceinline__ void pack16h(const float v[4][4], uint4 H[2]) {
  uint32_t hw[8];
  #pragma unroll
  for (int kk = 0; kk < 2; ++kk)
    #pragma unroll
    for (int w = 0; w < 4; ++w) {
      int mt = 2 * kk + (w >> 1), ie = 2 * (w & 1);
      uint32_t r;
      asm("v_cvt_pk_bf16_f32 %0, %1, %2" : "=v"(r) : "v"(v[mt][ie]), "v"(v[mt][ie + 1]));
      hw[kk * 4 + w] = r;
    }
  H[0] = (uint4){hw[0], hw[1], hw[2], hw[3]};
  H[1] = (uint4){hw[4], hw[5], hw[6], hw[7]};
}

// butterfly reduce across the four 16-lane groups
__device__ __forceinline__ float xreduce(float v) {
  int t = __builtin_amdgcn_ds_swizzle(__float_as_int(v), 0x401F); // lane ^= 16
  v += __int_as_float(t);
  float a = v, b = v;
  asm volatile("v_permlane32_swap_b32 %0, %1" : "+v"(a), "+v"(b));
  return a + b;   // lane i: v[i] + v[i^32]
}

// Pre-split A = W^T into hi/lo bf16 A-frags. Frag f = (l*4+mt)*2+kk.
// Lane (r=lane&15, g=lane>>4): row_out = 16mt+r; slot (w,h) holds
// W^T[row_out][k] = Ws[l][k][row_out], k = 16*(2kk+(w>>1)) + 4g + 2*(w&1) + h.
__global__ void __launch_bounds__(64) prep_kernel(const float* __restrict__ Ws,
                                                  uint4* __restrict__ whi,
                                                  uint4* __restrict__ wlo) {
  int f = blockIdx.x, lane = threadIdx.x;
  int kk = f & 1, mt = (f >> 1) & 3, l = f >> 3;
  int r = lane & 15, g = lane >> 4;
  uint32_t hw[4], lw[4];
  #pragma unroll
  for (int w = 0; w < 4; ++w) {
    uint32_t uu[2], res[2];
    #pragma unroll
    for (int h = 0; h < 2; ++h) {
      int k = 16 * (2 * kk + (w >> 1)) + 4 * g + 2 * (w & 1) + h;
      float v = Ws[l * 4096 + k * 64 + 16 * mt + r];
      uu[h] = __float_as_uint(v);
      res[h] = __float_as_uint(v - __uint_as_float(uu[h] & 0xFFFF0000u));
    }
    hw[w] = prm_hi(uu[1], uu[0]);
    lw[w] = prm_hi(res[1], res[0]);
  }
  whi[f * 64 + lane] = (uint4){hw[0], hw[1], hw[2], hw[3]};
  wlo[f * 64 + lane] = (uint4){lw[0], lw[1], lw[2], lw[3]};
}

// 4 independent waves per 256-thread block; each wave owns 16 points (p = lane&15).
// State transposed (X^T) in MFMA C-layout; repack to B-frags is in-lane, zero LDS.
// Y: hi/lo 3-term MFMA; T0/T1: single RNE bf16, 2-term (full-precision W x rounded state).
__global__ void __launch_bounds__(256, 4) velprevec_kernel(
    const float* __restrict__ x, const float* __restrict__ Win,
    const float* __restrict__ bin, const float* __restrict__ bs,
    const float* __restrict__ Wout, const uint4* __restrict__ whi,
    const uint4* __restrict__ wlo, float* __restrict__ out) {
  const int lane = threadIdx.x & 63;
  const int wid  = threadIdx.x >> 6;
  const int p0 = (blockIdx.x * 4 + wid) * 16;
  const int p = lane & 15, g = lane >> 4;
  const int fb = 4 * g;

  // ---- layer 0: Y = x@Win + bin; T0 = Win row0, T1 = Win row1 ----
  const float* xp = &x[(p0 + p) * 3];
  float x0 = xp[0], x1 = xp[1], x2 = xp[2];

  uint4 BYh[2], BYl[2], B0h[2], B1h[2];
  {
    float Yv[4][4], T0v[4][4], T1v[4][4];
    #pragma unroll
    for (int mt = 0; mt < 4; ++mt) {
      f32x4 w0 = *(const f32x4*)&Win[      16 * mt + fb];
      f32x4 w1 = *(const f32x4*)&Win[ 64 + 16 * mt + fb];
      f32x4 w2 = *(const f32x4*)&Win[128 + 16 * mt + fb];
      f32x4 bb = *(const f32x4*)&bin[      16 * mt + fb];
      #pragma unroll
      for (int i = 0; i < 4; ++i) {
        Yv[mt][i]  = fmaf(x0, w0[i], fmaf(x1, w1[i], fmaf(x2, w2[i], bb[i])));
        T0v[mt][i] = w0[i];
        T1v[mt][i] = w1[i];
      }
    }
    pack16(Yv, BYh, BYl);
    pack16h(T0v, B0h);
    pack16h(T1v, B1h);
  }

  float T0n[4][4], T1n[4][4];

  // ---- 7 hidden layers, zero LDS ----
  #pragma unroll 1
  for (int l = 0; l < 7; ++l) {
    const uint4* ph  = whi + l * 8 * 64 + lane;
    const uint4* pl_ = wlo + l * 8 * 64 + lane;
    f32x4 aY[4], a0[4], a1[4];
    #pragma unroll
    for (int mt = 0; mt < 4; ++mt) {
      aY[mt] = (f32x4){0.f, 0.f, 0.f, 0.f};
      a0[mt] = (f32x4){0.f, 0.f, 0.f, 0.f};
      a1[mt] = (f32x4){0.f, 0.f, 0.f, 0.f};
    }
    #pragma unroll
    for (int kk = 0; kk < 2; ++kk) {
      uint4 Ah[4], Al[4];
      #pragma unroll
      for (int mt = 0; mt < 4; ++mt) {
        Ah[mt] = ph[(mt * 2 + kk) * 64];
        Al[mt] = pl_[(mt * 2 + kk) * 64];
      }
      bf16x8 bYh = bc(BYh[kk]), bYl = bc(BYl[kk]);
      bf16x8 b0 = bc(B0h[kk]), b1 = bc(B1h[kk]);
      #pragma unroll
      for (int mt = 0; mt < 4; ++mt) aY[mt] = mfma16(bc(Ah[mt]), bYh, aY[mt]);
      #pragma unroll
      for (int mt = 0; mt < 4; ++mt) a0[mt] = mfma16(bc(Ah[mt]), b0, a0[mt]);
      #pragma unroll
      for (int mt = 0; mt < 4; ++mt) a1[mt] = mfma16(bc(Ah[mt]), b1, a1[mt]);
      #pragma unroll
      for (int mt = 0; mt < 4; ++mt) aY[mt] = mfma16(bc(Ah[mt]), bYl, aY[mt]);
      #pragma unroll
      for (int mt = 0; mt < 4; ++mt) aY[mt] = mfma16(bc(Al[mt]), bYh, aY[mt]);
      #pragma unroll
      for (int mt = 0; mt < 4; ++mt) a0[mt] = mfma16(bc(Al[mt]), b0, a0[mt]);
      #pragma unroll
      for (int mt = 0; mt < 4; ++mt) a1[mt] = mfma16(bc(Al[mt]), b1, a1[mt]);
    }
    // epilogue: tanh + tangent scale, all in-register
    float Yn[4][4];
    #pragma unroll
    for (int mt = 0; mt < 4; ++mt) {
      f32x4 bb = *(const f32x4*)&bs[l * 64 + 16 * mt + fb];
      #pragma unroll
      for (int i = 0; i < 4; ++i) {
        float e = exp2_fast(fmaf(aY[mt][i], TANH_C, bb[i] * TANH_C));
        float r = rcp_fast(e + 1.f);
        float t = fmaf(-2.f, r, 1.f);     // tanh(z)
        float s = fmaf(-t, t, 1.f);       // sech^2(z)
        Yn[mt][i]  = t;
        T0n[mt][i] = s * a0[mt][i];
        T1n[mt][i] = s * a1[mt][i];
      }
    }
    if (l < 6) {
      pack16(Yn, BYh, BYl);
      pack16h(T0n, B0h);
      pack16h(T1n, B1h);
    }
  }

  // ---- output: J_{jo} = T_j . Wout[:,o];  u = [J10, -J00, J01, J11] ----
  float J00 = 0.f, J01 = 0.f, J10 = 0.f, J11 = 0.f;
  #pragma unroll
  for (int mt = 0; mt < 4; ++mt) {
    f32x4 wa = *(const f32x4*)&Wout[(16 * mt + fb) * 2];      // feats f0,f1: (W0,W1,W0,W1)
    f32x4 wb = *(const f32x4*)&Wout[(16 * mt + fb) * 2 + 4];  // feats f2,f3
    J00 = fmaf(T0n[mt][0], wa[0], fmaf(T0n[mt][1], wa[2], fmaf(T0n[mt][2], wb[0], fmaf(T0n[mt][3], wb[2], J00))));
    J01 = fmaf(T0n[mt][0], wa[1], fmaf(T0n[mt][1], wa[3], fmaf(T0n[mt][2], wb[1], fmaf(T0n[mt][3], wb[3], J01))));
    J10 = fmaf(T1n[mt][0], wa[0], fmaf(T1n[mt][1], wa[2], fmaf(T1n[mt][2], wb[0], fmaf(T1n[mt][3], wb[2], J10))));
    J11 = fmaf(T1n[mt][0], wa[1], fmaf(T1n[mt][1], wa[3], fmaf(T1n[mt][2], wb[1], fmaf(T1n[mt][3], wb[3], J11))));
  }
  J00 = xreduce(J00); J01 = xreduce(J01); J10 = xreduce(J10); J11 = xreduce(J11);
  float val = (g == 0) ? J10 : (g == 1) ? -J00 : (g == 2) ? J01 : J11;
  out[(p0 + p) * 4 + g] = val;
}

extern "C" void kernel_launch(void* const* d_in, const int* in_sizes, int n_in,
                              void* d_out, int out_size, void* d_ws, size_t ws_size,
                              hipStream_t stream) {
  const float* x    = (const float*)d_in[0];
  const float* Win  = (const float*)d_in[1];
  const float* bin  = (const float*)d_in[2];
  const float* Ws   = (const float*)d_in[3];
  const float* bs   = (const float*)d_in[4];
  const float* Wout = (const float*)d_in[5];
  float* out = (float*)d_out;

  uint4* whi = (uint4*)d_ws;
  uint4* wlo = whi + 56 * 64;

  int N = in_sizes[0] / 3;      // 524288

  prep_kernel<<<56, 64, 0, stream>>>(Ws, whi, wlo);
  velprevec_kernel<<<N / 64, 256, 0, stream>>>(x, Win, bin, bs, Wout, whi, wlo, out);
}